// Round 14
// baseline (30.729 us; speedup 1.0000x reference)
//
#include <hip/hip_runtime.h>

// ResonantHTT embedding via two pair tables (b-major layout, u-permuted T):
//   T[p01][b][us] (us = (u>>4) + (u&15)*4), F[p23][b][v]
//   out[n, u*16+v] = sum_b T[p01][b][us(u)] * F[p23][b][v]
// k_outA: TWO tokens per wave. lane = (tok=lane>>5, r=lane&15, vh=bit4).
// Lane tile: u in {k*16+r, k=0..3} x v in {vh*8..vh*8+7}  (acc[4][8]).
// T-loads: one instr per b covers BOTH tokens (512B unique, 2-way dup)
//   -> 8 instr/token (halves TD return traffic vs R12).
// F via wave-private LDS (2 rows, fully-unique staging, 2-way-bank reads).
// Stores: 8 NT f32x4 instrs (32B strips, merge in WC).

typedef float f32x4 __attribute__((ext_vector_type(4)));

__global__ __launch_bounds__(256) void k_tables(
    const float* __restrict__ core0, const float* __restrict__ core1,
    const float* __restrict__ core2, const float* __restrict__ core3,
    const float* __restrict__ phase,
    float* __restrict__ T, float* __restrict__ F)
{
  const int gid = blockIdx.x * 256 + threadIdx.x;
  const int lane = threadIdx.x & 63;
  // each 16-lane segment holds cos(phase[0..15]); shuffle per a
  const float cown = cosf(phase[lane & 15]);
  if (blockIdx.x < 1024) {
    // ---- T: 262144 outputs, one per thread, b-major + u-permuted write ----
    const int p01 = gid >> 10, r = gid & 1023;
    const int b = r >> 6, u = r & 63;
    const int D0 = u >> 3, d1 = u & 7;
    const int i0 = p01 >> 4, i1 = p01 & 15;
    const float* c0 = core0 + i0 * 128 + D0;          // [a] stride 8
    const float* c1 = core1 + i1 * 2048 + b * 8 + d1; // [a] stride 128
    float acc = 0.f;
    #pragma unroll
    for (int a = 0; a < 16; ++a) {
      const float ca = __shfl(cown, a, 16);
      acc += c0[a * 8] * ca * c1[a * 128];
    }
    const int us = (u >> 4) + (u & 15) * 4;           // store-permutation
    T[p01 * 1024 + b * 64 + us] = acc;
  } else {
    // ---- F: 65536 outputs, one per thread, coalesced b-major write ----
    const int o = gid - 262144;
    const int p23 = o >> 8, r = o & 255;
    const int b = r >> 4, v = r & 15;
    const int d2 = v >> 2, d3 = v & 3;
    const int i2 = p23 >> 4, i3 = p23 & 15;
    const float* c2 = core2 + i2 * 1024 + b * 64 + d2; // [c] stride 4
    const float* c3 = core3 + i3 * 64 + d3;            // [c] stride 4
    float acc = 0.f;
    #pragma unroll
    for (int c = 0; c < 16; ++c)
      acc += c2[c * 4] * c3[c * 4];
    F[p23 * 256 + b * 16 + v] = acc;
  }
}

__global__ __launch_bounds__(256) void k_outA(
    const int* __restrict__ ids, const float* __restrict__ T,
    const float* __restrict__ F, float* __restrict__ out)
{
  __shared__ float sF[4][512];                  // per wave: [tok][256]
  const int wv = threadIdx.x >> 6, lane = threadIdx.x & 63;
  const int tok = lane >> 5;                    // wave's token half
  const int l31 = lane & 31;
  const int r   = lane & 15;
  const int vh  = (lane >> 4) & 1;
  const int n   = blockIdx.x * 8 + wv * 2 + tok;
  const int id  = ids[n];
  const int p01 = id >> 8, p23 = id & 255;

  // ---- T: 16 loads; each covers both tokens' 256B b-slices (2-way dup).
  // treg[b][k] = T[p01][b][us=r*4+k]  ->  u = k*16 + r.
  f32x4 treg[16];
  const float* Tp = T + p01 * 1024 + r * 4;
  #pragma unroll
  for (int b = 0; b < 16; ++b)
    treg[b] = *reinterpret_cast<const f32x4*>(Tp + b * 64);

  // ---- F: stage this wave's 2 rows; each instr 1KB fully unique.
  float* tF = &sF[wv][tok * 256];
  #pragma unroll
  for (int c = 0; c < 2; ++c) {
    const f32x4 v = *reinterpret_cast<const f32x4*>(F + p23 * 256 + c * 128 + l31 * 4);
    *reinterpret_cast<f32x4*>(tF + c * 128 + l31 * 4) = v;   // dense write
  }
  __syncthreads();   // cross-lane LDS RAW ordering (R7 lesson)

  float acc[4][8];
  #pragma unroll
  for (int k = 0; k < 4; ++k)
    #pragma unroll
    for (int j = 0; j < 8; ++j) acc[k][j] = 0.f;

  #pragma unroll
  for (int b = 0; b < 16; ++b) {
    // v = vh*8 + {0..7}; two b128 reads; 2-way bank alias (free)
    const f32x4 f0 = *reinterpret_cast<const f32x4*>(tF + b * 16 + vh * 8);
    const f32x4 f1 = *reinterpret_cast<const f32x4*>(tF + b * 16 + vh * 8 + 4);
    const f32x4 t = treg[b];
    #pragma unroll
    for (int k = 0; k < 4; ++k) {
      const float tk = (k == 0) ? t.x : (k == 1) ? t.y : (k == 2) ? t.z : t.w;
      acc[k][0] += tk * f0.x; acc[k][1] += tk * f0.y;
      acc[k][2] += tk * f0.z; acc[k][3] += tk * f0.w;
      acc[k][4] += tk * f1.x; acc[k][5] += tk * f1.y;
      acc[k][6] += tk * f1.z; acc[k][7] += tk * f1.w;
    }
  }

  // out idx = n*1024 + (k*16+r)*16 + vh*8 + jc*4 + j
  float* op = out + (size_t)n * 1024 + r * 16 + vh * 8;
  #pragma unroll
  for (int k = 0; k < 4; ++k) {
    f32x4 lo = { acc[k][0], acc[k][1], acc[k][2], acc[k][3] };
    f32x4 hi = { acc[k][4], acc[k][5], acc[k][6], acc[k][7] };
    __builtin_nontemporal_store(lo, reinterpret_cast<f32x4*>(op + k * 256));
    __builtin_nontemporal_store(hi, reinterpret_cast<f32x4*>(op + k * 256 + 4));
  }
}

extern "C" void kernel_launch(void* const* d_in, const int* in_sizes, int n_in,
                              void* d_out, int out_size, void* d_ws, size_t ws_size,
                              hipStream_t stream) {
  const int*   ids   = (const int*)  d_in[0];
  const float* core0 = (const float*)d_in[1];
  const float* core1 = (const float*)d_in[2];
  const float* core2 = (const float*)d_in[3];
  const float* core3 = (const float*)d_in[4];
  const float* phase = (const float*)d_in[5];
  float* out = (float*)d_out;

  float* Tt = (float*)d_ws;                    // 1 MB
  float* Ft = (float*)d_ws + 262144;           // 256 KB

  const int tokens = in_sizes[0];              // 16384
  hipLaunchKernelGGL(k_tables, dim3(1280), dim3(256), 0, stream,
                     core0, core1, core2, core3, phase, Tt, Ft);
  hipLaunchKernelGGL(k_outA, dim3(tokens / 8), dim3(256), 0, stream,
                     ids, Tt, Ft, out);
}

// Round 15
// 24.699 us; speedup vs baseline: 1.2442x; 1.2442x over previous
//
#include <hip/hip_runtime.h>

// ResonantHTT embedding via two pair tables (b-major layouts):
//   T[p01][b][u] = sum_a core0[i0,0,a,D0]*cos(phase[a]) * core1[i1,a,b,d1]
//       p01 = i0*16+i1, u = D0*8+d1   -> 256 x 16 x 64 f32 = 1 MB
//   F[p23][b][v] = sum_c core2[i2,b,c,d2] * core3[i3,c,0,d3]
//       p23 = i2*16+i3, v = d2*4+d3   -> 256 x 16 x 16 f32 = 256 KB
// Per token: out[n, u*16+v] = sum_b T[p01][b][u] * F[p23][b][v]
// k_outB: one token/wave, LANE = u.
//   T: 16 x global_load_dword, 256B FULLY DENSE per instr (zero redundancy).
//   F: wave-uniform -> readfirstlane(p23) -> s_load_dwordx4 via K$ (scalar
//      pipe; off the TD and LDS pipes). FMA uses SGPR operand directly.
//   Store: lane's 16 outputs are one 64B row -> transpose via padded LDS
//      (stride 20 dwords, conflict-free) -> 4 contiguous 1KB NT stores.

typedef float f32x4 __attribute__((ext_vector_type(4)));

__global__ __launch_bounds__(256) void k_tables(
    const float* __restrict__ core0, const float* __restrict__ core1,
    const float* __restrict__ core2, const float* __restrict__ core3,
    const float* __restrict__ phase,
    float* __restrict__ T, float* __restrict__ F)
{
  const int gid = blockIdx.x * 256 + threadIdx.x;
  const int lane = threadIdx.x & 63;
  // each 16-lane segment holds cos(phase[0..15]); shuffle per a
  const float cown = cosf(phase[lane & 15]);
  if (blockIdx.x < 1024) {
    // ---- T: 262144 outputs, one per thread, b-major coalesced write ----
    const int p01 = gid >> 10, r = gid & 1023;
    const int b = r >> 6, u = r & 63;
    const int D0 = u >> 3, d1 = u & 7;
    const int i0 = p01 >> 4, i1 = p01 & 15;
    const float* c0 = core0 + i0 * 128 + D0;          // [a] stride 8
    const float* c1 = core1 + i1 * 2048 + b * 8 + d1; // [a] stride 128
    float acc = 0.f;
    #pragma unroll
    for (int a = 0; a < 16; ++a) {
      const float ca = __shfl(cown, a, 16);
      acc += c0[a * 8] * ca * c1[a * 128];
    }
    T[p01 * 1024 + b * 64 + u] = acc;                 // natural u layout
  } else {
    // ---- F: 65536 outputs, one per thread, coalesced b-major write ----
    const int o = gid - 262144;
    const int p23 = o >> 8, r = o & 255;
    const int b = r >> 4, v = r & 15;
    const int d2 = v >> 2, d3 = v & 3;
    const int i2 = p23 >> 4, i3 = p23 & 15;
    const float* c2 = core2 + i2 * 1024 + b * 64 + d2; // [c] stride 4
    const float* c3 = core3 + i3 * 64 + d3;            // [c] stride 4
    float acc = 0.f;
    #pragma unroll
    for (int c = 0; c < 16; ++c)
      acc += c2[c * 4] * c3[c * 4];
    F[p23 * 256 + b * 16 + v] = acc;
  }
}

__global__ __launch_bounds__(256) void k_outB(
    const int* __restrict__ ids, const float* __restrict__ T,
    const float* __restrict__ F, float* __restrict__ out)
{
  __shared__ float xp[4][64 * 20];              // 5KB/wave transpose buffer
  const int wv = threadIdx.x >> 6, lane = threadIdx.x & 63;
  const int n = blockIdx.x * 4 + wv;            // one token per wave
  const int id = ids[n];
  const int p01 = id >> 8;
  const int p23 = __builtin_amdgcn_readfirstlane(id & 255);  // force SGPR
  const float* __restrict__ Fp = F + p23 * 256; // uniform base -> s_load path

  // ---- T: u = lane; 16 dense 256B dword loads, zero redundancy ----
  float treg[16];
  const float* Tp = T + p01 * 1024 + lane;
  #pragma unroll
  for (int b = 0; b < 16; ++b)
    treg[b] = Tp[b * 64];

  float acc[16];                                 // acc[v], u = lane
  #pragma unroll
  for (int v = 0; v < 16; ++v) acc[v] = 0.f;

  #pragma unroll
  for (int b = 0; b < 16; ++b) {
    // wave-uniform F row chunk: s_load_dwordx4 x4 (K$/scalar pipe)
    const f32x4 f0 = *reinterpret_cast<const f32x4*>(Fp + b * 16);
    const f32x4 f1 = *reinterpret_cast<const f32x4*>(Fp + b * 16 + 4);
    const f32x4 f2 = *reinterpret_cast<const f32x4*>(Fp + b * 16 + 8);
    const f32x4 f3 = *reinterpret_cast<const f32x4*>(Fp + b * 16 + 12);
    const float tb = treg[b];
    acc[0]  = fmaf(tb, f0.x, acc[0]);  acc[1]  = fmaf(tb, f0.y, acc[1]);
    acc[2]  = fmaf(tb, f0.z, acc[2]);  acc[3]  = fmaf(tb, f0.w, acc[3]);
    acc[4]  = fmaf(tb, f1.x, acc[4]);  acc[5]  = fmaf(tb, f1.y, acc[5]);
    acc[6]  = fmaf(tb, f1.z, acc[6]);  acc[7]  = fmaf(tb, f1.w, acc[7]);
    acc[8]  = fmaf(tb, f2.x, acc[8]);  acc[9]  = fmaf(tb, f2.y, acc[9]);
    acc[10] = fmaf(tb, f2.z, acc[10]); acc[11] = fmaf(tb, f2.w, acc[11]);
    acc[12] = fmaf(tb, f3.x, acc[12]); acc[13] = fmaf(tb, f3.y, acc[13]);
    acc[14] = fmaf(tb, f3.z, acc[14]); acc[15] = fmaf(tb, f3.w, acc[15]);
  }

  // ---- transpose via padded LDS (stride 20 dwords: conflict-free) ----
  float* xw = xp[wv];
  #pragma unroll
  for (int e = 0; e < 4; ++e) {
    f32x4 w = { acc[e*4+0], acc[e*4+1], acc[e*4+2], acc[e*4+3] };
    *reinterpret_cast<f32x4*>(xw + lane * 20 + e * 4) = w;
  }
  __syncthreads();   // cross-lane LDS RAW ordering (R7 lesson)

  // store k: lane l -> out[n*1024 + k*256 + l*4 + j]
  //   = element (u = k*16 + (l>>2), v = (l&3)*4 + j), read from xw.
  // Each store instr: 64 lanes x 16B CONTIGUOUS = 1KB, full 64B lines.
  float* op = out + (size_t)n * 1024 + lane * 4;
  #pragma unroll
  for (int k = 0; k < 4; ++k) {
    const f32x4 r = *reinterpret_cast<const f32x4*>(
        xw + (k * 16 + (lane >> 2)) * 20 + (lane & 3) * 4);
    __builtin_nontemporal_store(r, reinterpret_cast<f32x4*>(op + k * 256));
  }
}

extern "C" void kernel_launch(void* const* d_in, const int* in_sizes, int n_in,
                              void* d_out, int out_size, void* d_ws, size_t ws_size,
                              hipStream_t stream) {
  const int*   ids   = (const int*)  d_in[0];
  const float* core0 = (const float*)d_in[1];
  const float* core1 = (const float*)d_in[2];
  const float* core2 = (const float*)d_in[3];
  const float* core3 = (const float*)d_in[4];
  const float* phase = (const float*)d_in[5];
  float* out = (float*)d_out;

  float* Tt = (float*)d_ws;                    // 1 MB
  float* Ft = (float*)d_ws + 262144;           // 256 KB

  const int tokens = in_sizes[0];              // 16384
  hipLaunchKernelGGL(k_tables, dim3(1280), dim3(256), 0, stream,
                     core0, core1, core2, core3, phase, Tt, Ft);
  hipLaunchKernelGGL(k_outB, dim3(tokens / 4), dim3(256), 0, stream,
                     ids, Tt, Ft, out);
}

// Round 16
// 24.096 us; speedup vs baseline: 1.2752x; 1.0250x over previous
//
#include <hip/hip_runtime.h>

// ResonantHTT embedding via two pair tables (b-major layout, u-permuted T):
//   T[p01][b][us] (us = (u>>4) + (u&15)*4), F[p23][b][v]
//   out[n, u*16+v] = sum_b T[p01][b][us(u)] * F[p23][b][v]
// k_out9: one token/wave; T in regs (16 coalesced f32x4 loads), F via LDS,
// 4 contiguous 1KB NT stores (R12 = best, 23.9us).
// R16 change: XCD-aware block swizzle in k_out so each XCD writes one
// contiguous 8MB slice of out -> DRAM row locality for the write stream.

typedef float f32x4 __attribute__((ext_vector_type(4)));

__global__ __launch_bounds__(256) void k_tables(
    const float* __restrict__ core0, const float* __restrict__ core1,
    const float* __restrict__ core2, const float* __restrict__ core3,
    const float* __restrict__ phase,
    float* __restrict__ T, float* __restrict__ F)
{
  const int gid = blockIdx.x * 256 + threadIdx.x;
  const int lane = threadIdx.x & 63;
  // each 16-lane segment holds cos(phase[0..15]); shuffle per a
  const float cown = cosf(phase[lane & 15]);
  if (blockIdx.x < 1024) {
    // ---- T: 262144 outputs, one per thread, b-major + u-permuted write ----
    const int p01 = gid >> 10, r = gid & 1023;
    const int b = r >> 6, u = r & 63;
    const int D0 = u >> 3, d1 = u & 7;
    const int i0 = p01 >> 4, i1 = p01 & 15;
    const float* c0 = core0 + i0 * 128 + D0;          // [a] stride 8
    const float* c1 = core1 + i1 * 2048 + b * 8 + d1; // [a] stride 128
    float acc = 0.f;
    #pragma unroll
    for (int a = 0; a < 16; ++a) {
      const float ca = __shfl(cown, a, 16);
      acc += c0[a * 8] * ca * c1[a * 128];
    }
    const int us = (u >> 4) + (u & 15) * 4;           // store-permutation
    T[p01 * 1024 + b * 64 + us] = acc;
  } else {
    // ---- F: 65536 outputs, one per thread, coalesced b-major write ----
    const int o = gid - 262144;
    const int p23 = o >> 8, r = o & 255;
    const int b = r >> 4, v = r & 15;
    const int d2 = v >> 2, d3 = v & 3;
    const int i2 = p23 >> 4, i3 = p23 & 15;
    const float* c2 = core2 + i2 * 1024 + b * 64 + d2; // [c] stride 4
    const float* c3 = core3 + i3 * 64 + d3;            // [c] stride 4
    float acc = 0.f;
    #pragma unroll
    for (int c = 0; c < 16; ++c)
      acc += c2[c * 4] * c3[c * 4];
    F[p23 * 256 + b * 16 + v] = acc;
  }
}

__global__ __launch_bounds__(256) void k_out9(
    const int* __restrict__ ids, const float* __restrict__ T,
    const float* __restrict__ F, float* __restrict__ out)
{
  __shared__ float sF[4][256];                  // 1KB per wave
  const int wv = threadIdx.x >> 6, lane = threadIdx.x & 63;
  // XCD swizzle: 4096 blocks, 8 XCDs (bid%8 = XCD, round-robin dispatch).
  // XCD x handles contiguous token-groups [x*512, (x+1)*512) -> its writes
  // land in one contiguous 8MB slice of out (DRAM row locality).
  const int g = (blockIdx.x & 7) * 512 + (blockIdx.x >> 3);
  const int n = g * 4 + wv;                     // one token per wave
  const int id = ids[n];                        // wave-uniform
  const int p01 = id >> 8, p23 = id & 255;
  const int ug = lane >> 2, vg = lane & 3;

  // ---- T-slice into registers: 16 coalesced float4 loads (independent).
  // treg[b][e] = T[p01][b][ug*4+e] which is actual u = e*16 + ug.
  f32x4 treg[16];
  const float* Tp = T + p01 * 1024 + ug * 4;
  #pragma unroll
  for (int b = 0; b < 16; ++b)
    treg[b] = *reinterpret_cast<const f32x4*>(Tp + b * 64);

  // ---- F-row (1KB): ONE coalesced load -> wave-private LDS ----
  float* tF = sF[wv];
  {
    const f32x4 v = *reinterpret_cast<const f32x4*>(F + p23 * 256 + lane * 4);
    *reinterpret_cast<f32x4*>(tF + lane * 4) = v;
  }
  __syncthreads();   // cross-lane LDS RAW ordering (R7 lesson)

  float acc[4][4];   // acc[e][j]: u = e*16+ug, v = vg*4+j
  #pragma unroll
  for (int i = 0; i < 4; ++i)
    #pragma unroll
    for (int j = 0; j < 4; ++j) acc[i][j] = 0.f;

  #pragma unroll
  for (int b = 0; b < 16; ++b) {
    // 4 distinct 16B segments, 16-way same-addr broadcast: conflict-free
    const f32x4 f = *reinterpret_cast<const f32x4*>(tF + b * 16 + vg * 4);
    const f32x4 t = treg[b];
    acc[0][0] += t.x*f.x; acc[0][1] += t.x*f.y; acc[0][2] += t.x*f.z; acc[0][3] += t.x*f.w;
    acc[1][0] += t.y*f.x; acc[1][1] += t.y*f.y; acc[1][2] += t.y*f.z; acc[1][3] += t.y*f.w;
    acc[2][0] += t.z*f.x; acc[2][1] += t.z*f.y; acc[2][2] += t.z*f.z; acc[2][3] += t.z*f.w;
    acc[3][0] += t.w*f.x; acc[3][1] += t.w*f.y; acc[3][2] += t.w*f.z; acc[3][3] += t.w*f.w;
  }

  // Output position for acc[e][j]: u*16+v = (e*16+ug)*16 + vg*4+j
  //   = e*256 + lane*4 + j -> store e is 64 lanes x 16B CONTIGUOUS = 1KB.
  float* op = out + (size_t)n * 1024 + lane * 4;
  #pragma unroll
  for (int e = 0; e < 4; ++e) {
    f32x4 v4 = { acc[e][0], acc[e][1], acc[e][2], acc[e][3] };
    __builtin_nontemporal_store(v4, reinterpret_cast<f32x4*>(op + e * 256));
  }
}

extern "C" void kernel_launch(void* const* d_in, const int* in_sizes, int n_in,
                              void* d_out, int out_size, void* d_ws, size_t ws_size,
                              hipStream_t stream) {
  const int*   ids   = (const int*)  d_in[0];
  const float* core0 = (const float*)d_in[1];
  const float* core1 = (const float*)d_in[2];
  const float* core2 = (const float*)d_in[3];
  const float* core3 = (const float*)d_in[4];
  const float* phase = (const float*)d_in[5];
  float* out = (float*)d_out;

  float* Tt = (float*)d_ws;                    // 1 MB
  float* Ft = (float*)d_ws + 262144;           // 256 KB

  const int tokens = in_sizes[0];              // 16384
  hipLaunchKernelGGL(k_tables, dim3(1280), dim3(256), 0, stream,
                     core0, core1, core2, core3, phase, Tt, Ft);
  hipLaunchKernelGGL(k_out9, dim3(tokens / 4), dim3(256), 0, stream,
                     ids, Tt, Ft, out);
}